// Round 17
// baseline (1187.618 us; speedup 1.0000x reference)
//
#include <hip/hip_runtime.h>
#include <stdint.h>

// Sparse top-k attention (B=4,N=2048,H=16,DH=64, topk=64).
// Selection matches numpy f32: q32/k32 ~f32-exact (6-term 3-word-split MFMA);
// bulk scores 3-term 2-word MFMA stored f16; keys as packed monotone-u16
// codes; 13-step integer bisection, guaranteed bracket, ballot+popc counts;
// provably-safe windows (DELTA=2.5e-3); boundary candidates recomputed f64,
// ranked exactly with numpy tie semantics. v in f16.
// attn_k: 16 waves/WG (1024,8), one row/wave; XCD-grouped mapping (K/V
// L2-resident); QK^T stages ONLY kh in 128-col tiles (16KB, all threads
// stage -> barriers halved 66->34), km read direct from L2 in consumers
// (wait hidden under kh MFMAs); T14 prefetch; setprio around MFMA.

typedef __attribute__((ext_vector_type(8))) short short8;
typedef __attribute__((ext_vector_type(4))) float floatx4;
typedef _Float16 f16x2 __attribute__((ext_vector_type(2)));

#define Bn   4
#define Nn   2048
#define Hn   16
#define BHn  (Bn*Hn)
#define DELTA 0.0025f

__device__ __forceinline__ float bf2f(unsigned short u) {
  union { unsigned int i; float f; } v; v.i = ((unsigned int)u) << 16; return v.f;
}
__device__ __forceinline__ unsigned short f2bf(float f) {
  union { float f; unsigned int i; } v; v.f = f;
  unsigned int r = v.i + 0x7fffu + ((v.i >> 16) & 1u);
  return (unsigned short)(r >> 16);
}
__device__ __forceinline__ floatx4 mfma16(short8 a, short8 b, floatx4 c) {
  return __builtin_amdgcn_mfma_f32_16x16x32_bf16(a, b, c, 0, 0, 0);
}
__device__ __forceinline__ void split2(float x, unsigned short& h, unsigned short& m) {
  h = f2bf(x);
  m = f2bf(x - bf2f(h));
}
__device__ __forceinline__ void split3(float x, unsigned short& h, unsigned short& m, unsigned short& l) {
  h = f2bf(x);
  float r = x - bf2f(h);
  m = f2bf(r);
  l = f2bf(r - bf2f(m));
}
// monotone u16 code of an f16 bit pattern (total order on values)
__device__ __forceinline__ unsigned int mapf(float f) {
  union { _Float16 h; unsigned short s; } u; u.h = (_Float16)f;
  unsigned int b = (unsigned int)u.s;
  return (b & 0x8000u) ? (b ^ 0xFFFFu) : (b | 0x8000u);
}
__device__ __forceinline__ float unmapf(unsigned int c) {
  unsigned int b = (c & 0x8000u) ? (c ^ 0x8000u) : (c ^ 0xFFFFu);
  union { _Float16 h; unsigned short s; } u; u.s = (unsigned short)b;
  return (float)u.h;
}

// ---- W[K][N] f32 -> T0/T1/T2[N][K] bf16 3-word split
__global__ __launch_bounds__(256)
void transpose_split3(const float* __restrict__ W,
                      unsigned short* __restrict__ T0,
                      unsigned short* __restrict__ T1,
                      unsigned short* __restrict__ T2,
                      int K, int Ncols)
{
  __shared__ float tile[32][33];
  int k0 = blockIdx.y * 32, n0 = blockIdx.x * 32;
  int tx = threadIdx.x & 31, ty = threadIdx.x >> 5;
  for (int s = 0; s < 32; s += 8)
    tile[ty + s][tx] = W[(size_t)(k0 + ty + s) * Ncols + n0 + tx];
  __syncthreads();
  for (int s = 0; s < 32; s += 8) {
    float x = tile[tx][ty + s];
    unsigned short h, m, l;
    split3(x, h, m, l);
    size_t o = (size_t)(n0 + ty + s) * K + k0 + tx;
    T0[o] = h; T1[o] = m; T2[o] = l;
  }
}

// ---- W[K][N] f32 -> T0/T1[N][K] bf16 2-word split
__global__ __launch_bounds__(256)
void transpose_split2(const float* __restrict__ W,
                      unsigned short* __restrict__ T0,
                      unsigned short* __restrict__ T1,
                      int K, int Ncols)
{
  __shared__ float tile[32][33];
  int k0 = blockIdx.y * 32, n0 = blockIdx.x * 32;
  int tx = threadIdx.x & 31, ty = threadIdx.x >> 5;
  for (int s = 0; s < 32; s += 8)
    tile[ty + s][tx] = W[(size_t)(k0 + ty + s) * Ncols + n0 + tx];
  __syncthreads();
  for (int s = 0; s < 32; s += 8) {
    float x = tile[tx][ty + s];
    unsigned short h, m;
    split2(x, h, m);
    size_t o = (size_t)(n0 + ty + s) * K + k0 + tx;
    T0[o] = h; T1[o] = m;
  }
}

__global__ __launch_bounds__(256)
void convert_bf16(const float* __restrict__ in, unsigned short* __restrict__ outp, int n) {
  int i = blockIdx.x * 256 + threadIdx.x;
  if (i < n) outp[i] = f2bf(in[i]);
}

// ---- QKV GEMM: A(f32) split3 on the fly, B 3-word. q/k tiles: 6 MFMA terms
// (~f32-exact), outputs f32 + 2-word bf16. Pure-V tiles (n0>=1024): 3 terms,
// f16 output.
__global__ __launch_bounds__(256)
void gemm_qkv(const float* __restrict__ A,
              const unsigned short* __restrict__ B0,
              const unsigned short* __restrict__ B1,
              const unsigned short* __restrict__ B2,
              const float* __restrict__ bias,
              float* __restrict__ O32,
              unsigned short* __restrict__ Oh,
              unsigned short* __restrict__ Om,
              _Float16* __restrict__ Vh,
              int K, float scale)
{
  __shared__ unsigned short lA[3][128 * 40];
  __shared__ unsigned short lB[3][128 * 40];
  const int tid = threadIdx.x;
  const int lane = tid & 63;
  const int m0 = blockIdx.y * 128, n0 = blockIdx.x * 128;
  const bool vblk = (n0 >= 1024);
  const int wid = tid >> 6, wm = wid >> 1, wn = wid & 1;
  const int fr = lane & 15, fq = lane >> 4;
  floatx4 acc[4][4] = {};

  for (int k0 = 0; k0 < K; k0 += 32) {
    __syncthreads();
    #pragma unroll
    for (int p = 0; p < 2; p++) {
      int c = tid + p * 256;
      int row = c >> 2, kc = (c & 3) * 8;
      size_t go = (size_t)(m0 + row) * K + k0 + kc;
      float4 v0 = *(const float4*)&A[go];
      float4 v1 = *(const float4*)&A[go + 4];
      union { unsigned short u[8]; uint4 q; } hh, mm, ll;
      float xs[8] = {v0.x, v0.y, v0.z, v0.w, v1.x, v1.y, v1.z, v1.w};
      #pragma unroll
      for (int e = 0; e < 8; e++) split3(xs[e], hh.u[e], mm.u[e], ll.u[e]);
      *(uint4*)&lA[0][row * 40 + kc] = hh.q;
      *(uint4*)&lA[1][row * 40 + kc] = mm.q;
      size_t bo = (size_t)(n0 + row) * K + k0 + kc;
      *(uint4*)&lB[0][row * 40 + kc] = *(const uint4*)&B0[bo];
      *(uint4*)&lB[1][row * 40 + kc] = *(const uint4*)&B1[bo];
      if (!vblk) {
        *(uint4*)&lA[2][row * 40 + kc] = ll.q;
        *(uint4*)&lB[2][row * 40 + kc] = *(const uint4*)&B2[bo];
      }
    }
    __syncthreads();
    short8 af0[4], af1[4], af2[4], bf0[4], bf1[4], bf2v[4];
    #pragma unroll
    for (int t = 0; t < 4; t++) {
      int ao = (wm * 64 + t * 16 + fr) * 40 + 8 * fq;
      int bo2 = (wn * 64 + t * 16 + fr) * 40 + 8 * fq;
      af0[t] = *(const short8*)&lA[0][ao];
      af1[t] = *(const short8*)&lA[1][ao];
      bf0[t] = *(const short8*)&lB[0][bo2];
      bf1[t] = *(const short8*)&lB[1][bo2];
      if (!vblk) {
        af2[t] = *(const short8*)&lA[2][ao];
        bf2v[t] = *(const short8*)&lB[2][bo2];
      }
    }
    #pragma unroll
    for (int mi = 0; mi < 4; mi++)
      #pragma unroll
      for (int ni = 0; ni < 4; ni++) {
        acc[mi][ni] = mfma16(af0[mi], bf0[ni], acc[mi][ni]);
        acc[mi][ni] = mfma16(af0[mi], bf1[ni], acc[mi][ni]);
        acc[mi][ni] = mfma16(af1[mi], bf0[ni], acc[mi][ni]);
        if (!vblk) {
          acc[mi][ni] = mfma16(af1[mi], bf1[ni], acc[mi][ni]);
          acc[mi][ni] = mfma16(af0[mi], bf2v[ni], acc[mi][ni]);
          acc[mi][ni] = mfma16(af2[mi], bf0[ni], acc[mi][ni]);
        }
      }
  }
  // C/D frag: row=(lane>>4)*4+rg, col=lane&15
  #pragma unroll
  for (int mi = 0; mi < 4; mi++)
    #pragma unroll
    for (int ni = 0; ni < 4; ni++) {
      int nl = n0 + wn * 64 + ni * 16 + fr;
      float bv = bias[nl];
      #pragma unroll
      for (int rg = 0; rg < 4; rg++) {
        int ml = m0 + wm * 64 + mi * 16 + fq * 4 + rg;
        float val = (acc[mi][ni][rg] + bv) * scale;
        int bb = ml >> 11, ii = ml & 2047;
        int hh2 = (nl & 1023) >> 6, dd = nl & 63;
        size_t idx = (((size_t)bb * Hn + hh2) * Nn + ii) * 64 + dd;
        if (!vblk) {
          O32[idx] = val;
          unsigned short h, m;
          split2(val, h, m);
          Oh[idx] = h; Om[idx] = m;
        } else {
          Vh[idx] = (_Float16)val;
        }
      }
    }
}

// ---- output GEMM: A f32 split2 on the fly, B 2-word, 3 terms, f32 out.
__global__ __launch_bounds__(256)
void gemm_out(const float* __restrict__ A,
              const unsigned short* __restrict__ B0,
              const unsigned short* __restrict__ B1,
              const float* __restrict__ bias,
              float* __restrict__ O32,
              int Ncols, int K)
{
  __shared__ unsigned short lA[2][128 * 40];
  __shared__ unsigned short lB[2][128 * 40];
  const int tid = threadIdx.x;
  const int lane = tid & 63;
  const int m0 = blockIdx.y * 128, n0 = blockIdx.x * 128;
  const int wid = tid >> 6, wm = wid >> 1, wn = wid & 1;
  const int fr = lane & 15, fq = lane >> 4;
  floatx4 acc[4][4] = {};

  for (int k0 = 0; k0 < K; k0 += 32) {
    __syncthreads();
    #pragma unroll
    for (int p = 0; p < 2; p++) {
      int c = tid + p * 256;
      int row = c >> 2, kc = (c & 3) * 8;
      size_t go = (size_t)(m0 + row) * K + k0 + kc;
      float4 v0 = *(const float4*)&A[go];
      float4 v1 = *(const float4*)&A[go + 4];
      union { unsigned short u[8]; uint4 q; } hh, mm;
      float xs[8] = {v0.x, v0.y, v0.z, v0.w, v1.x, v1.y, v1.z, v1.w};
      #pragma unroll
      for (int e = 0; e < 8; e++) split2(xs[e], hh.u[e], mm.u[e]);
      *(uint4*)&lA[0][row * 40 + kc] = hh.q;
      *(uint4*)&lA[1][row * 40 + kc] = mm.q;
      size_t bo = (size_t)(n0 + row) * K + k0 + kc;
      *(uint4*)&lB[0][row * 40 + kc] = *(const uint4*)&B0[bo];
      *(uint4*)&lB[1][row * 40 + kc] = *(const uint4*)&B1[bo];
    }
    __syncthreads();
    short8 af[2][4], bfr[2][4];
    #pragma unroll
    for (int s = 0; s < 2; s++)
      #pragma unroll
      for (int t = 0; t < 4; t++) {
        af[s][t]  = *(const short8*)&lA[s][(wm * 64 + t * 16 + fr) * 40 + 8 * fq];
        bfr[s][t] = *(const short8*)&lB[s][(wn * 64 + t * 16 + fr) * 40 + 8 * fq];
      }
    #pragma unroll
    for (int mi = 0; mi < 4; mi++)
      #pragma unroll
      for (int ni = 0; ni < 4; ni++) {
        acc[mi][ni] = mfma16(af[0][mi], bfr[0][ni], acc[mi][ni]);
        acc[mi][ni] = mfma16(af[0][mi], bfr[1][ni], acc[mi][ni]);
        acc[mi][ni] = mfma16(af[1][mi], bfr[0][ni], acc[mi][ni]);
      }
  }
  #pragma unroll
  for (int mi = 0; mi < 4; mi++)
    #pragma unroll
    for (int ni = 0; ni < 4; ni++) {
      int nl = n0 + wn * 64 + ni * 16 + fr;
      float bv = bias[nl];
      #pragma unroll
      for (int rg = 0; rg < 4; rg++) {
        int ml = m0 + wm * 64 + mi * 16 + fq * 4 + rg;
        O32[(size_t)ml * Ncols + nl] = acc[mi][ni][rg] + bv;
      }
    }
}

// ---- attention: one WG (16 waves / 1024 thr) = 16 query rows; wave w owns
// row w. XCD-grouped block mapping. QK^T: 16 iterations of 128 cols; all
// 1024 threads stage kh (16KB tile, T14 prefetch); 8 MFMA waves each do one
// 16-col strip with km direct from L2 (wait hidden under kh MFMAs).
// Keys as packed u16 codes; ballot+popc bisection; S/qE col-swizzled.
__global__ __launch_bounds__(1024, 8)
void attn_k(const unsigned short* __restrict__ qh,
            const unsigned short* __restrict__ qm,
            const unsigned short* __restrict__ kh,
            const unsigned short* __restrict__ km,
            const _Float16* __restrict__ vh,
            const float* __restrict__ q32,
            const float* __restrict__ k32,
            const unsigned short* __restrict__ relbf,
            const float* __restrict__ rel32,
            const float* __restrict__ gating,
            const int* __restrict__ topkp,
            float* __restrict__ inner)
{
  extern __shared__ char smem[];
  _Float16* S = (_Float16*)smem;                          // [16][2048] 65536B
  unsigned short* Kt = (unsigned short*)(smem + 65536);   // [128][64] 16384B
  _Float16* qE = (_Float16*)Kt;                           // [16][256] reuse

  // XCD-grouped mapping: 8192 blocks; wgid&7 = XCD (round-robin dispatch);
  // each XCD gets bh in [xcd*8, xcd*8+8) entirely.
  const int wgid = blockIdx.x;
  const int xcd = wgid & 7;
  const int idx = wgid >> 3;
  const int bh = xcd * 8 + (idx >> 7);
  const int ib = idx & 127;
  const int i0 = ib * 16;
  const int b = bh >> 4, h = bh & 15;
  const int tid = threadIdx.x;
  const int lane = tid & 63, w = tid >> 6;      // w in [0,16)
  const int fr = lane & 15, fq = lane >> 4;
  const int topk = topkp[0];
  const size_t kbase = (size_t)bh * Nn * 64;

  // q A-fragments, 2-word
  const size_t qoff = ((size_t)bh * Nn + i0) * 64;
  const size_t qf = qoff + (size_t)fr * 64 + 8 * fq;
  const short8 aqh0 = *(const short8*)&qh[qf];
  const short8 aqh1 = *(const short8*)&qh[qf + 32];
  const short8 aqm0 = *(const short8*)&qm[qf];
  const short8 aqm1 = *(const short8*)&qm[qf + 32];

  // QK^T: 16 iterations x 128 cols. All threads stage kh (16 B each);
  // consumer waves 0-7 each compute strip w (16 cols): 4 kh-MFMAs from LDS
  // + 2 km-MFMAs with operands direct from global (L2-resident).
  {
    const int srow = tid >> 3, sch = tid & 7;           // [0,128) x [0,8)
    const int sdst = srow * 64 + ((sch ^ (srow & 7)) * 8);   // chunk swizzle
    const size_t sgbase = kbase + (size_t)srow * 64 + sch * 8;
    uint4 rr = *(const uint4*)&kh[sgbase];

    for (int jt = 0; jt < 16; jt++) {
      __syncthreads();                         // waves done reading Kt(jt-1)
      *(uint4*)&Kt[sdst] = rr;                 // write tile jt (128 cols kh)
      if (jt + 1 < 16)
        rr = *(const uint4*)&kh[sgbase + (size_t)(jt + 1) * 8192];
      __syncthreads();                         // Kt(jt) ready
      if (w < 8) {
        int row16 = w * 16 + fr, r7 = fr & 7;
        int b0 = row16 * 64 + ((fq ^ r7) * 8);
        int b1 = row16 * 64 + (((fq + 4) ^ r7) * 8);
        const size_t kf = kbase + (size_t)(jt * 128 + row16) * 64 + 8 * fq;
        __builtin_amdgcn_s_setprio(1);
        floatx4 c = {};
        short8 m0 = *(const short8*)&km[kf];             // L2-hit, issued early
        short8 m1 = *(const short8*)&km[kf + 32];
        {
          short8 h0 = *(const short8*)&Kt[b0];
          short8 h1 = *(const short8*)&Kt[b1];
          c = mfma16(aqh0, h0, c);
          c = mfma16(aqm0, h0, c);
          c = mfma16(aqh1, h1, c);
          c = mfma16(aqm1, h1, c);
        }
        c = mfma16(aqh0, m0, c);
        c = mfma16(aqh1, m1, c);
        __builtin_amdgcn_s_setprio(0);
        int colsw = jt * 128 + ((w ^ fq) * 16) + fr;   // col ^ ((row>>2)<<4)
        #pragma unroll
        for (int rg = 0; rg < 4; rg++)
          S[(fq * 4 + rg) * 2048 + colsw] = (_Float16)c[rg];
      }
    }
  }
  __syncthreads();

  // qE[i_local][r] = q_i . rel_r : wave w computes strip w (16 rel rows)
  {
    size_t rf = (size_t)(w * 16 + fr) * 64 + 8 * fq;
    short8 rb0 = *(const short8*)&relbf[rf];
    short8 rb1 = *(const short8*)&relbf[rf + 32];
    floatx4 c = {};
    c = mfma16(aqh0, rb0, c); c = mfma16(aqh1, rb1, c);
    c = mfma16(aqm0, rb0, c); c = mfma16(aqm1, rb1, c);
    int colsw = ((w ^ fq) * 16) + fr;
    #pragma unroll
    for (int rg = 0; rg < 4; rg++)
      qE[(fq * 4 + rg) * 256 + colsw] = (_Float16)c[rg];
  }
  __syncthreads();

  // ---- keys-build: row w into 16 packed-code regs (pk_add + packed map)
  const int r = w;
  const int i = i0 + r;
  const int X = (r >> 2) << 4;
  _Float16* S0 = S + r * 2048;
  const _Float16* qE0 = qE + r * 256;
  union pun { unsigned int u; f16x2 h; };
  pun cAp, cCp;
  cAp.h[0] = qE0[255 ^ X]; cAp.h[1] = cAp.h[0];
  cCp.h[0] = qE0[X];       cCp.h[1] = cCp.h[0];
  const int swl = (2 * lane) ^ X;

  unsigned int kk[16];
  unsigned int mh = 0, ml = 0;
  #pragma unroll
  for (int e = 0; e < 16; e++) {
    const int jb = 128 * e;
    pun sv, ev;
    sv.u = *(const unsigned int*)&S0[jb + swl];
    if (jb + 127 <= i) ev = cAp;
    else if (jb >= i + 256) ev = cCp;
    else {
      const int j0 = jb + 2 * lane;
      int c0 = i - j0 + 256; c0 = c0 < 0 ? 0 : (c0 > 255 ? 255 : c0);
      int c1 = i - j0 + 255; c1 = c1 < 0 ? 0 : (c1 > 255 ? 255 : c1);
      ev.h[0] = qE0[c0 ^ X]; ev.h[1] = qE0[c1 ^ X];
    }
    pun rv; rv.h = sv.h + ev.h;                 // v_pk_add_f16
    unsigned int u = rv.u;
    unsigned int sgn = (u >> 15) & 0x00010001u;
    unsigned int code = u ^ (sgn * 0x7FFFu + 0x80008000u);
    kk[e] = code;
    unsigned int chi = code & 0xFFFF0000u, clo = code << 16;
    mh = mh > chi ? mh : chi;
    ml = ml > clo ? ml : clo;
  }
  unsigned int umax = (mh > ml ? mh : ml) >> 16;
  // wave max and min-of-lane-maxes (guaranteed bracket: cnt(mn) >= 64)
  unsigned int mxu = umax, mnu = umax;
  #pragma unroll
  for (int d = 1; d < 64; d <<= 1) {
    unsigned int o1 = (unsigned int)__shfl_xor((int)mxu, d);
    unsigned int o2 = (unsigned int)__shfl_xor((int)mnu, d);
    mxu = o1 > mxu ? o1 : mxu;
    mnu = o2 < mnu ? o2 : mnu;
  }
  const float mxv = unmapf(mxu);

  // 13-step integer bisection on codes; counts via ballot + popc (scalar)
  unsigned int lo = mnu, hi = mxu + 1;
  #pragma unroll 1
  for (int it = 0; it < 13; it++) {
    unsigned int mid = (lo + hi) >> 1;
    int cnt = 0;
    #pragma unroll
    for (int e = 0; e < 16; e++) {
      cnt += (int)__popcll(__ballot((kk[e] >> 16) >= mid));
      cnt += (int)__popcll(__ballot((kk[e] & 0xffffu) >= mid));
    }
    if (cnt >= topk) lo = mid; else hi = mid;
  }
  // provably-safe windows (code-domain, +-1 code conservative slop)
  const float Cv = unmapf(hi) + 2.0f * DELTA;
  const float Lv = unmapf(lo) - 2.0f * DELTA;
  const unsigned int Cu = mapf(Cv) + 1;
  int Lsi = (int)mapf(Lv) - 1;
  const unsigned int Lu = Lsi < 0 ? 0u : (unsigned int)Lsi;

  // scratch aliased into this row's S span (keys fully in regs)
  char* sb = (char*)S0;
  unsigned int* Pk = (unsigned int*)sb;     // [128] j | code<<16
  int*   Jc = (int*)(sb + 512);             // [64]
  float* Sx = (float*)(sb + 768);           // [64]
  float* P2 = (float*)(sb + 1024);          // [128]
  asm volatile("" ::: "memory");
  const unsigned long long lmlt = (1ull << lane) - 1ull;

  int base = 0, mc = 0;
  #pragma unroll
  for (int t = 0; t < 32; t++) {
    unsigned int code = (t & 1) ? (kk[t >> 1] >> 16) : (kk[t >> 1] & 0xffffu);
    const int j = 2 * lane + 128 * (t >> 1) + (t & 1);
    bool dk = code >= Cu;
    bool cd = (code >= Lu) && !dk;
    unsigned long long mk = __ballot(dk);
    if (dk) { int pos = base + __popcll(mk & lmlt); Pk[pos] = (unsigned int)j | (code << 16); }
    base += __popcll(mk);
    mk = __ballot(cd);
    if (cd) { int pos = mc + __popcll(mk & lmlt); if (pos < 64) Jc[pos] = j; }
    mc += __popcll(mk);
  }
  if (mc > 64) mc = 64;
  asm volatile("" ::: "memory");

  // exact recompute of candidates (f64 accum from ~f32-exact q32/k32)
  const double qv = (double)q32[((size_t)bh * Nn + i) * 64 + lane];
  #pragma unroll 1
  for (int c2 = 0; c2 < mc; c2++) {
    int j = Jc[c2];
    int ridx = i - j + 256; ridx = ridx < 0 ? 0 : (ridx > 255 ? 255 : ridx);
    double t2 = qv * ((double)k32[((size_t)bh * Nn + j) * 64 + lane] +
                      (double)rel32[ridx * 64 + lane]);
    #pragma unroll
    for (int d = 1; d < 64; d <<= 1) t2 += __shfl_xor(t2, d);
    if (lane == 0) Sx[c2] = (float)t2;
  }
  asm volatile("" ::: "memory");

  // rank by exact score; numpy tie semantics (== vk kept)
  const int need = topk - base;
  float myx = (lane < mc) ? Sx[lane] : -3.0e38f;
  int rank = 0;
  #pragma unroll 1
  for (int c2 = 0; c2 < mc; c2++) {
    float o = Sx[c2];
    rank += (o > myx || (o == myx && c2 < lane)) ? 1 : 0;
  }
  unsigned long long bm = __ballot((lane < mc) && (rank == need - 1));
  float vk = bm ? __shfl(myx, (int)__ffsll(bm) - 1) : 3.0e38f;
  bool ck = (lane < mc) && ((rank < need) || (myx == vk));
  unsigned long long km2 = __ballot(ck);
  float pb = 0.f;
  if (ck) {
    int pos = base + __popcll(km2 & lmlt);
    Pk[pos] = (unsigned int)Jc[lane];
    pb = __expf(myx - mxv);
    P2[pos] = pb;                        // boundary p exact (from f64 score)
  }
  const int nk = base + __popcll(km2);
  // exp for sure-keeps (from quantized codes) + denom
  float ps = pb;
  #pragma unroll 1
  for (int t = lane; t < base; t += 64) {
    float val = unmapf(Pk[t] >> 16);
    float p = __expf(val - mxv);
    P2[t] = p; ps += p;
  }
  #pragma unroll
  for (int d = 1; d < 64; d <<= 1) ps += __shfl_xor(ps, d);
  const float coef = gating[(size_t)b * Nn + i] / ps;
  asm volatile("" ::: "memory");

  // PV gather (f16 v), 4-deep ILP; first 64 guaranteed (nk >= topk = 64)
  const _Float16* vbp = vh + (size_t)bh * Nn * 64 + lane;
  float a0 = 0.f, a1 = 0.f, a2 = 0.f, a3 = 0.f;
  #pragma unroll 1
  for (int t = 0; t < 64; t += 4) {
    int j0 = (int)(Pk[t] & 0xffffu), j1 = (int)(Pk[t + 1] & 0xffffu);
    int j2 = (int)(Pk[t + 2] & 0xffffu), j3 = (int)(Pk[t + 3] & 0xffffu);
    float p0 = P2[t], p1 = P2[t + 1], p2 = P2[t + 2], p3 = P2[t + 3];
    a0 += p0 * (float)vbp[(size_t)j0 * 64];
    a1 += p1 * (float)vbp[(size_t)j1 * 64];
    a2 += p2 * (float)vbp[(size_t)j2 * 64];
    a3 += p3 * (float)vbp[(size_t)j3 * 64];
  }
  #pragma unroll 1
  for (int t = 64; t < nk; t++)
    a0 += P2[t] * (float)vbp[(size_t)(Pk[t] & 0xffffu) * 64];
  inner[((size_t)b * Nn + i) * 1024 + h * 64 + lane] = (a0 + a1 + a2 + a3) * coef;
}

extern "C" void kernel_launch(void* const* d_in, const int* in_sizes, int n_in,
                              void* d_out, int out_size, void* d_ws, size_t ws_size,
                              hipStream_t stream) {
  const float* x      = (const float*)d_in[0];
  const float* gating = (const float*)d_in[1];
  const float* Wq     = (const float*)d_in[2];
  const float* bq     = (const float*)d_in[3];
  const float* Wkv    = (const float*)d_in[4];
  const float* bkv    = (const float*)d_in[5];
  const float* Wo     = (const float*)d_in[6];
  const float* bo     = (const float*)d_in[7];
  const float* rel    = (const float*)d_in[8];
  const int*   topk   = (const int*)d_in[10];
  float* out = (float*)d_out;

  char* ws = (char*)d_ws;
  size_t off = 0;
  auto alloc = [&](size_t bytes) -> void* {
    void* p = ws + off; off += (bytes + 255) & ~(size_t)255; return p;
  };
  unsigned short* Wqt0 = (unsigned short*)alloc(1024ull * 1024 * 2);
  unsigned short* Wqt1 = (unsigned short*)alloc(1024ull * 1024 * 2);
  unsigned short* Wqt2 = (unsigned short*)alloc(1024ull * 1024 * 2);
  unsigned short* Wkt0 = (unsigned short*)alloc(2048ull * 1024 * 2);
  unsigned short* Wkt1 = (unsigned short*)alloc(2048ull * 1024 * 2);
  unsigned short* Wkt2 = (unsigned short*)alloc(2048ull * 1024 * 2);
  unsigned short* Wot0 = (unsigned short*)alloc(1024ull * 1024 * 2);
  unsigned short* Wot1 = (unsigned short*)alloc(1024ull * 1024 * 2);
  unsigned short* relbf = (unsigned short*)alloc(256ull * 64 * 2);
  float* q32 = (float*)alloc((size_t)BHn * Nn * 64 * 4);
  float* k32 = (float*)alloc((size_t)BHn * Nn * 64 * 4);
  unsigned short* qhb = (unsigned short*)alloc((size_t)BHn * Nn * 64 * 2);
  unsigned short* qmb = (unsigned short*)alloc((size_t)BHn * Nn * 64 * 2);
  unsigned short* khb = (unsigned short*)alloc((size_t)BHn * Nn * 64 * 2);
  unsigned short* kmb = (unsigned short*)alloc((size_t)BHn * Nn * 64 * 2);
  _Float16* vhb = (_Float16*)alloc((size_t)BHn * Nn * 64 * 2);
  float* inner = (float*)alloc((size_t)Bn * Nn * 1024 * 4);
  if (off > ws_size) return;  // workspace too small -> loud validation fail

  size_t shmem = 65536 + 16384;  // 81920 B -> 2 WG/CU (160 KiB total)
  (void)hipFuncSetAttribute((const void*)attn_k,
                            hipFuncAttributeMaxDynamicSharedMemorySize, (int)shmem);

  transpose_split3<<<dim3(32, 32), 256, 0, stream>>>(Wq, Wqt0, Wqt1, Wqt2, 1024, 1024);
  transpose_split3<<<dim3(64, 32), 256, 0, stream>>>(Wkv, Wkt0, Wkt1, Wkt2, 1024, 2048);
  transpose_split2<<<dim3(32, 32), 256, 0, stream>>>(Wo, Wot0, Wot1, 1024, 1024);
  convert_bf16<<<dim3(64), 256, 0, stream>>>(rel, relbf, 256 * 64);

  // q = (x@Wq + bq) * 1/8  (scale folded; exact pow2)
  gemm_qkv<<<dim3(8, 64), 256, 0, stream>>>(x, Wqt0, Wqt1, Wqt2, bq,
      q32, qhb, qmb, vhb, 1024, 0.125f);
  // k | v = x@Wkv + bkv
  gemm_qkv<<<dim3(16, 64), 256, 0, stream>>>(x, Wkt0, Wkt1, Wkt2, bkv,
      k32, khb, kmb, vhb, 1024, 1.0f);

  attn_k<<<dim3(8192), 1024, shmem, stream>>>(qhb, qmb, khb, kmb, vhb,
      q32, k32, relbf, rel, gating, topk, inner);

  // out = inner@Wo + bo
  gemm_out<<<dim3(8, 64), 256, 0, stream>>>(inner, Wot0, Wot1, bo,
      out, 1024, 1024);
}

// Round 18
// 1115.496 us; speedup vs baseline: 1.0647x; 1.0647x over previous
//
#include <hip/hip_runtime.h>
#include <stdint.h>

// Sparse top-k attention (B=4,N=2048,H=16,DH=64, topk=64).  FINAL (r16 best).
// Selection matches numpy f32: q32/k32 ~f32-exact (6-term 3-word-split MFMA);
// bulk scores 3-term 2-word MFMA stored f16; keys as packed monotone-u16
// codes; 13-step integer bisection, guaranteed bracket, ballot+popc counts;
// provably-safe windows (DELTA=2.5e-3); boundary candidates recomputed f64,
// ranked exactly with numpy tie semantics. v in f16.
// attn_k: 16 waves/WG (1024,8), one row/wave; XCD-grouped block mapping
// (K/V L2-resident); LDS-staged QK^T with T14 async-stage split; 2-group
// B-frag reads; setprio around MFMA; PV static-64 main loop.

typedef __attribute__((ext_vector_type(8))) short short8;
typedef __attribute__((ext_vector_type(4))) float floatx4;
typedef _Float16 f16x2 __attribute__((ext_vector_type(2)));

#define Bn   4
#define Nn   2048
#define Hn   16
#define BHn  (Bn*Hn)
#define DELTA 0.0025f

__device__ __forceinline__ float bf2f(unsigned short u) {
  union { unsigned int i; float f; } v; v.i = ((unsigned int)u) << 16; return v.f;
}
__device__ __forceinline__ unsigned short f2bf(float f) {
  union { float f; unsigned int i; } v; v.f = f;
  unsigned int r = v.i + 0x7fffu + ((v.i >> 16) & 1u);
  return (unsigned short)(r >> 16);
}
__device__ __forceinline__ floatx4 mfma16(short8 a, short8 b, floatx4 c) {
  return __builtin_amdgcn_mfma_f32_16x16x32_bf16(a, b, c, 0, 0, 0);
}
__device__ __forceinline__ void split2(float x, unsigned short& h, unsigned short& m) {
  h = f2bf(x);
  m = f2bf(x - bf2f(h));
}
__device__ __forceinline__ void split3(float x, unsigned short& h, unsigned short& m, unsigned short& l) {
  h = f2bf(x);
  float r = x - bf2f(h);
  m = f2bf(r);
  l = f2bf(r - bf2f(m));
}
// monotone u16 code of an f16 bit pattern (total order on values)
__device__ __forceinline__ unsigned int mapf(float f) {
  union { _Float16 h; unsigned short s; } u; u.h = (_Float16)f;
  unsigned int b = (unsigned int)u.s;
  return (b & 0x8000u) ? (b ^ 0xFFFFu) : (b | 0x8000u);
}
__device__ __forceinline__ float unmapf(unsigned int c) {
  unsigned int b = (c & 0x8000u) ? (c ^ 0x8000u) : (c ^ 0xFFFFu);
  union { _Float16 h; unsigned short s; } u; u.s = (unsigned short)b;
  return (float)u.h;
}

// ---- W[K][N] f32 -> T0/T1/T2[N][K] bf16 3-word split
__global__ __launch_bounds__(256)
void transpose_split3(const float* __restrict__ W,
                      unsigned short* __restrict__ T0,
                      unsigned short* __restrict__ T1,
                      unsigned short* __restrict__ T2,
                      int K, int Ncols)
{
  __shared__ float tile[32][33];
  int k0 = blockIdx.y * 32, n0 = blockIdx.x * 32;
  int tx = threadIdx.x & 31, ty = threadIdx.x >> 5;
  for (int s = 0; s < 32; s += 8)
    tile[ty + s][tx] = W[(size_t)(k0 + ty + s) * Ncols + n0 + tx];
  __syncthreads();
  for (int s = 0; s < 32; s += 8) {
    float x = tile[tx][ty + s];
    unsigned short h, m, l;
    split3(x, h, m, l);
    size_t o = (size_t)(n0 + ty + s) * K + k0 + tx;
    T0[o] = h; T1[o] = m; T2[o] = l;
  }
}

// ---- W[K][N] f32 -> T0/T1[N][K] bf16 2-word split
__global__ __launch_bounds__(256)
void transpose_split2(const float* __restrict__ W,
                      unsigned short* __restrict__ T0,
                      unsigned short* __restrict__ T1,
                      int K, int Ncols)
{
  __shared__ float tile[32][33];
  int k0 = blockIdx.y * 32, n0 = blockIdx.x * 32;
  int tx = threadIdx.x & 31, ty = threadIdx.x >> 5;
  for (int s = 0; s < 32; s += 8)
    tile[ty + s][tx] = W[(size_t)(k0 + ty + s) * Ncols + n0 + tx];
  __syncthreads();
  for (int s = 0; s < 32; s += 8) {
    float x = tile[tx][ty + s];
    unsigned short h, m;
    split2(x, h, m);
    size_t o = (size_t)(n0 + ty + s) * K + k0 + tx;
    T0[o] = h; T1[o] = m;
  }
}

__global__ __launch_bounds__(256)
void convert_bf16(const float* __restrict__ in, unsigned short* __restrict__ outp, int n) {
  int i = blockIdx.x * 256 + threadIdx.x;
  if (i < n) outp[i] = f2bf(in[i]);
}

// ---- QKV GEMM: A(f32) split3 on the fly, B 3-word. q/k tiles: 6 MFMA terms
// (~f32-exact), outputs f32 + 2-word bf16. Pure-V tiles (n0>=1024): 3 terms,
// f16 output.
__global__ __launch_bounds__(256)
void gemm_qkv(const float* __restrict__ A,
              const unsigned short* __restrict__ B0,
              const unsigned short* __restrict__ B1,
              const unsigned short* __restrict__ B2,
              const float* __restrict__ bias,
              float* __restrict__ O32,
              unsigned short* __restrict__ Oh,
              unsigned short* __restrict__ Om,
              _Float16* __restrict__ Vh,
              int K, float scale)
{
  __shared__ unsigned short lA[3][128 * 40];
  __shared__ unsigned short lB[3][128 * 40];
  const int tid = threadIdx.x;
  const int lane = tid & 63;
  const int m0 = blockIdx.y * 128, n0 = blockIdx.x * 128;
  const bool vblk = (n0 >= 1024);
  const int wid = tid >> 6, wm = wid >> 1, wn = wid & 1;
  const int fr = lane & 15, fq = lane >> 4;
  floatx4 acc[4][4] = {};

  for (int k0 = 0; k0 < K; k0 += 32) {
    __syncthreads();
    #pragma unroll
    for (int p = 0; p < 2; p++) {
      int c = tid + p * 256;
      int row = c >> 2, kc = (c & 3) * 8;
      size_t go = (size_t)(m0 + row) * K + k0 + kc;
      float4 v0 = *(const float4*)&A[go];
      float4 v1 = *(const float4*)&A[go + 4];
      union { unsigned short u[8]; uint4 q; } hh, mm, ll;
      float xs[8] = {v0.x, v0.y, v0.z, v0.w, v1.x, v1.y, v1.z, v1.w};
      #pragma unroll
      for (int e = 0; e < 8; e++) split3(xs[e], hh.u[e], mm.u[e], ll.u[e]);
      *(uint4*)&lA[0][row * 40 + kc] = hh.q;
      *(uint4*)&lA[1][row * 40 + kc] = mm.q;
      size_t bo = (size_t)(n0 + row) * K + k0 + kc;
      *(uint4*)&lB[0][row * 40 + kc] = *(const uint4*)&B0[bo];
      *(uint4*)&lB[1][row * 40 + kc] = *(const uint4*)&B1[bo];
      if (!vblk) {
        *(uint4*)&lA[2][row * 40 + kc] = ll.q;
        *(uint4*)&lB[2][row * 40 + kc] = *(const uint4*)&B2[bo];
      }
    }
    __syncthreads();
    short8 af0[4], af1[4], af2[4], bf0[4], bf1[4], bf2v[4];
    #pragma unroll
    for (int t = 0; t < 4; t++) {
      int ao = (wm * 64 + t * 16 + fr) * 40 + 8 * fq;
      int bo2 = (wn * 64 + t * 16 + fr) * 40 + 8 * fq;
      af0[t] = *(const short8*)&lA[0][ao];
      af1[t] = *(const short8*)&lA[1][ao];
      bf0[t] = *(const short8*)&lB[0][bo2];
      bf1[t] = *(const short8*)&lB[1][bo2];
      if (!vblk) {
        af2[t] = *(const short8*)&lA[2][ao];
        bf2v[t] = *(const short8*)&lB[2][bo2];
      }
    }
    #pragma unroll
    for (int mi = 0; mi < 4; mi++)
      #pragma unroll
      for (int ni = 0; ni < 4; ni++) {
        acc[mi][ni] = mfma16(af0[mi], bf0[ni], acc[mi][ni]);
        acc[mi][ni] = mfma16(af0[mi], bf1[ni], acc[mi][ni]);
        acc[mi][ni] = mfma16(af1[mi], bf0[ni], acc[mi][ni]);
        if (!vblk) {
          acc[mi][ni] = mfma16(af1[mi], bf1[ni], acc[mi][ni]);
          acc[mi][ni] = mfma16(af0[mi], bf2v[ni], acc[mi][ni]);
          acc[mi][ni] = mfma16(af2[mi], bf0[ni], acc[mi][ni]);
        }
      }
  }
  // C/D frag: row=(lane>>4)*4+rg, col=lane&15
  #pragma unroll
  for (int mi = 0; mi < 4; mi++)
    #pragma unroll
    for (int ni = 0; ni < 4; ni++) {
      int nl = n0 + wn * 64 + ni * 16 + fr;
      float bv = bias[nl];
      #pragma unroll
      for (int rg = 0; rg < 4; rg++) {
        int ml = m0 + wm * 64 + mi * 16 + fq * 4 + rg;
        float val = (acc[mi][ni][rg] + bv) * scale;
        int bb = ml >> 11, ii = ml & 2047;
        int hh2 = (nl & 1023) >> 6, dd = nl & 63;
        size_t idx = (((size_t)bb * Hn + hh2) * Nn + ii) * 64 + dd;
        if (!vblk) {
          O32[idx] = val;
          unsigned short h, m;
          split2(val, h, m);
          Oh[idx] = h; Om[idx] = m;
        } else {
          Vh[idx] = (_Float16)val;
        }
      }
    }
}

// ---- output GEMM: A f32 split2 on the fly, B 2-word, 3 terms, f32 out.
__global__ __launch_bounds__(256)
void gemm_out(const float* __restrict__ A,
              const unsigned short* __restrict__ B0,
              const unsigned short* __restrict__ B1,
              const float* __restrict__ bias,
              float* __restrict__ O32,
              int Ncols, int K)
{
  __shared__ unsigned short lA[2][128 * 40];
  __shared__ unsigned short lB[2][128 * 40];
  const int tid = threadIdx.x;
  const int lane = tid & 63;
  const int m0 = blockIdx.y * 128, n0 = blockIdx.x * 128;
  const int wid = tid >> 6, wm = wid >> 1, wn = wid & 1;
  const int fr = lane & 15, fq = lane >> 4;
  floatx4 acc[4][4] = {};

  for (int k0 = 0; k0 < K; k0 += 32) {
    __syncthreads();
    #pragma unroll
    for (int p = 0; p < 2; p++) {
      int c = tid + p * 256;
      int row = c >> 2, kc = (c & 3) * 8;
      size_t go = (size_t)(m0 + row) * K + k0 + kc;
      float4 v0 = *(const float4*)&A[go];
      float4 v1 = *(const float4*)&A[go + 4];
      union { unsigned short u[8]; uint4 q; } hh, mm;
      float xs[8] = {v0.x, v0.y, v0.z, v0.w, v1.x, v1.y, v1.z, v1.w};
      #pragma unroll
      for (int e = 0; e < 8; e++) split2(xs[e], hh.u[e], mm.u[e]);
      *(uint4*)&lA[0][row * 40 + kc] = hh.q;
      *(uint4*)&lA[1][row * 40 + kc] = mm.q;
      size_t bo = (size_t)(n0 + row) * K + k0 + kc;
      *(uint4*)&lB[0][row * 40 + kc] = *(const uint4*)&B0[bo];
      *(uint4*)&lB[1][row * 40 + kc] = *(const uint4*)&B1[bo];
    }
    __syncthreads();
    short8 af[2][4], bfr[2][4];
    #pragma unroll
    for (int s = 0; s < 2; s++)
      #pragma unroll
      for (int t = 0; t < 4; t++) {
        af[s][t]  = *(const short8*)&lA[s][(wm * 64 + t * 16 + fr) * 40 + 8 * fq];
        bfr[s][t] = *(const short8*)&lB[s][(wn * 64 + t * 16 + fr) * 40 + 8 * fq];
      }
    #pragma unroll
    for (int mi = 0; mi < 4; mi++)
      #pragma unroll
      for (int ni = 0; ni < 4; ni++) {
        acc[mi][ni] = mfma16(af[0][mi], bfr[0][ni], acc[mi][ni]);
        acc[mi][ni] = mfma16(af[0][mi], bfr[1][ni], acc[mi][ni]);
        acc[mi][ni] = mfma16(af[1][mi], bfr[0][ni], acc[mi][ni]);
      }
  }
  #pragma unroll
  for (int mi = 0; mi < 4; mi++)
    #pragma unroll
    for (int ni = 0; ni < 4; ni++) {
      int nl = n0 + wn * 64 + ni * 16 + fr;
      float bv = bias[nl];
      #pragma unroll
      for (int rg = 0; rg < 4; rg++) {
        int ml = m0 + wm * 64 + mi * 16 + fq * 4 + rg;
        O32[(size_t)ml * Ncols + nl] = acc[mi][ni][rg] + bv;
      }
    }
}

// ---- attention: one WG (16 waves / 1024 thr) = 16 query rows; wave w owns
// row w. 1D grid with XCD-grouped mapping (each XCD owns 8 bh). LDS-staged
// QK^T with async-stage split; setprio(1) around MFMA cluster. Keys as
// packed u16 codes; ballot+popc bisection. S/qE col-swizzled.
__global__ __launch_bounds__(1024, 8)
void attn_k(const unsigned short* __restrict__ qh,
            const unsigned short* __restrict__ qm,
            const unsigned short* __restrict__ kh,
            const unsigned short* __restrict__ km,
            const _Float16* __restrict__ vh,
            const float* __restrict__ q32,
            const float* __restrict__ k32,
            const unsigned short* __restrict__ relbf,
            const float* __restrict__ rel32,
            const float* __restrict__ gating,
            const int* __restrict__ topkp,
            float* __restrict__ inner)
{
  extern __shared__ char smem[];
  _Float16* S = (_Float16*)smem;                          // [16][2048] 65536B
  unsigned short* KtH = (unsigned short*)(smem + 65536);  // [64][64] 8192B
  unsigned short* KtM = KtH + 4096;                       // [64][64] 8192B
  _Float16* qE = (_Float16*)KtH;                          // [16][256] reuse

  // XCD-grouped mapping: 8192 blocks; wgid&7 = XCD (round-robin dispatch);
  // each XCD gets bh in [xcd*8, xcd*8+8) entirely.
  const int wgid = blockIdx.x;
  const int xcd = wgid & 7;
  const int idx = wgid >> 3;
  const int bh = xcd * 8 + (idx >> 7);
  const int ib = idx & 127;
  const int i0 = ib * 16;
  const int b = bh >> 4, h = bh & 15;
  const int tid = threadIdx.x;
  const int lane = tid & 63, w = tid >> 6;      // w in [0,16)
  const int fr = lane & 15, fq = lane >> 4;
  const int topk = topkp[0];

  // q A-fragments, 2-word
  const size_t qoff = ((size_t)bh * Nn + i0) * 64;
  const size_t qf = qoff + (size_t)fr * 64 + 8 * fq;
  const short8 aqh0 = *(const short8*)&qh[qf];
  const short8 aqh1 = *(const short8*)&qh[qf + 32];
  const short8 aqm0 = *(const short8*)&qm[qf];
  const short8 aqm1 = *(const short8*)&qm[qf + 32];

  // QK^T: 32 tiles of 64 cols; async-stage split (T14): regs hold tile jt,
  // global load for jt+1 issued before the MFMA barrier.
  {
    const int sel = tid >> 9;                 // 0: KtH, 1: KtM
    const int row = (tid >> 3) & 63, ch = tid & 7;
    const int dst = row * 64 + ((ch ^ (row & 7)) * 8);   // chunk swizzle
    unsigned short* T = sel ? KtM : KtH;
    const unsigned short* src = sel ? km : kh;
    const size_t gbase = (size_t)bh * Nn * 64 + (size_t)row * 64 + ch * 8;
    uint4 rr = *(const uint4*)&src[gbase];

    for (int jt = 0; jt < 32; jt++) {
      __syncthreads();                         // waves done reading Kt(jt-1)
      *(uint4*)&T[dst] = rr;                   // write tile jt
      if (jt + 1 < 32)
        rr = *(const uint4*)&src[gbase + (size_t)(jt + 1) * 4096];
      __syncthreads();                         // Kt(jt) ready
      if (w < 8 && ((jt & 1) == (w >> 2))) {
        int wc = w & 3;
        int row16 = wc * 16 + fr, r7 = fr & 7;
        int b0 = row16 * 64 + ((fq ^ r7) * 8);
        int b1 = row16 * 64 + (((fq + 4) ^ r7) * 8);
        __builtin_amdgcn_s_setprio(1);
        floatx4 c = {};
        {
          short8 kh0 = *(const short8*)&KtH[b0];
          short8 kh1 = *(const short8*)&KtH[b1];
          c = mfma16(aqh0, kh0, c);
          c = mfma16(aqm0, kh0, c);
          c = mfma16(aqh1, kh1, c);
          c = mfma16(aqm1, kh1, c);
        }
        {
          short8 km0 = *(const short8*)&KtM[b0];
          short8 km1 = *(const short8*)&KtM[b1];
          c = mfma16(aqh0, km0, c);
          c = mfma16(aqh1, km1, c);
        }
        __builtin_amdgcn_s_setprio(0);
        int colsw = jt * 64 + ((wc ^ fq) * 16) + fr;   // col ^ ((row>>2)<<4)
        #pragma unroll
        for (int rg = 0; rg < 4; rg++)
          S[(fq * 4 + rg) * 2048 + colsw] = (_Float16)c[rg];
      }
    }
  }
  __syncthreads();

  // qE[i_local][r] = q_i . rel_r : wave w computes strip w (16 rel rows)
  {
    size_t rf = (size_t)(w * 16 + fr) * 64 + 8 * fq;
    short8 rb0 = *(const short8*)&relbf[rf];
    short8 rb1 = *(const short8*)&relbf[rf + 32];
    floatx4 c = {};
    c = mfma16(aqh0, rb0, c); c = mfma16(aqh1, rb1, c);
    c = mfma16(aqm0, rb0, c); c = mfma16(aqm1, rb1, c);
    int colsw = ((w ^ fq) * 16) + fr;
    #pragma unroll
    for (int rg = 0; rg < 4; rg++)
      qE[(fq * 4 + rg) * 256 + colsw] = (_Float16)c[rg];
  }
  __syncthreads();

  // ---- keys-build: row w into 16 packed-code regs (pk_add + packed map)
  const int r = w;
  const int i = i0 + r;
  const int X = (r >> 2) << 4;
  _Float16* S0 = S + r * 2048;
  const _Float16* qE0 = qE + r * 256;
  union pun { unsigned int u; f16x2 h; };
  pun cAp, cCp;
  cAp.h[0] = qE0[255 ^ X]; cAp.h[1] = cAp.h[0];
  cCp.h[0] = qE0[X];       cCp.h[1] = cCp.h[0];
  const int swl = (2 * lane) ^ X;

  unsigned int kk[16];
  unsigned int mh = 0, ml = 0;
  #pragma unroll
  for (int e = 0; e < 16; e++) {
    const int jb = 128 * e;
    pun sv, ev;
    sv.u = *(const unsigned int*)&S0[jb + swl];
    if (jb + 127 <= i) ev = cAp;
    else if (jb >= i + 256) ev = cCp;
    else {
      const int j0 = jb + 2 * lane;
      int c0 = i - j0 + 256; c0 = c0 < 0 ? 0 : (c0 > 255 ? 255 : c0);
      int c1 = i - j0 + 255; c1 = c1 < 0 ? 0 : (c1 > 255 ? 255 : c1);
      ev.h[0] = qE0[c0 ^ X]; ev.h[1] = qE0[c1 ^ X];
    }
    pun rv; rv.h = sv.h + ev.h;                 // v_pk_add_f16
    unsigned int u = rv.u;
    unsigned int sgn = (u >> 15) & 0x00010001u;
    unsigned int code = u ^ (sgn * 0x7FFFu + 0x80008000u);
    kk[e] = code;
    unsigned int chi = code & 0xFFFF0000u, clo = code << 16;
    mh = mh > chi ? mh : chi;
    ml = ml > clo ? ml : clo;
  }
  unsigned int umax = (mh > ml ? mh : ml) >> 16;
  // wave max and min-of-lane-maxes (guaranteed bracket: cnt(mn) >= 64)
  unsigned int mxu = umax, mnu = umax;
  #pragma unroll
  for (int d = 1; d < 64; d <<= 1) {
    unsigned int o1 = (unsigned int)__shfl_xor((int)mxu, d);
    unsigned int o2 = (unsigned int)__shfl_xor((int)mnu, d);
    mxu = o1 > mxu ? o1 : mxu;
    mnu = o2 < mnu ? o2 : mnu;
  }
  const float mxv = unmapf(mxu);

  // 13-step integer bisection on codes; counts via ballot + popc (scalar)
  unsigned int lo = mnu, hi = mxu + 1;
  #pragma unroll 1
  for (int it = 0; it < 13; it++) {
    unsigned int mid = (lo + hi) >> 1;
    int cnt = 0;
    #pragma unroll
    for (int e = 0; e < 16; e++) {
      cnt += (int)__popcll(__ballot((kk[e] >> 16) >= mid));
      cnt += (int)__popcll(__ballot((kk[e] & 0xffffu) >= mid));
    }
    if (cnt >= topk) lo = mid; else hi = mid;
  }
  // provably-safe windows (code-domain, +-1 code conservative slop)
  const float Cv = unmapf(hi) + 2.0f * DELTA;
  const float Lv = unmapf(lo) - 2.0f * DELTA;
  const unsigned int Cu = mapf(Cv) + 1;
  int Lsi = (int)mapf(Lv) - 1;
  const unsigned int Lu = Lsi < 0 ? 0u : (unsigned int)Lsi;

  // scratch aliased into this row's S span (keys fully in regs)
  char* sb = (char*)S0;
  unsigned int* Pk = (unsigned int*)sb;     // [128] j | code<<16
  int*   Jc = (int*)(sb + 512);             // [64]
  float* Sx = (float*)(sb + 768);           // [64]
  float* P2 = (float*)(sb + 1024);          // [128]
  asm volatile("" ::: "memory");
  const unsigned long long lmlt = (1ull << lane) - 1ull;

  int base = 0, mc = 0;
  #pragma unroll
  for (int t = 0; t < 32; t++) {
    unsigned int code = (t & 1) ? (kk[t >> 1] >> 16) : (kk[t >> 1] & 0xffffu);
    const int j = 2 * lane + 128 * (t >> 1) + (t & 1);
    bool dk = code >= Cu;
    bool cd = (code >= Lu) && !dk;
    unsigned long long mk = __ballot(dk);
    if (dk) { int pos = base + __popcll(mk & lmlt); Pk[pos] = (unsigned int)j | (code << 16); }
    base += __popcll(mk);
    mk = __ballot(cd);
    if (cd) { int pos = mc + __popcll(mk & lmlt); if (pos < 64) Jc[pos] = j; }
    mc += __popcll(mk);
  }
  if (mc > 64) mc = 64;
  asm volatile("" ::: "memory");

  // exact recompute of candidates (f64 accum from ~f32-exact q32/k32)
  const double qv = (double)q32[((size_t)bh * Nn + i) * 64 + lane];
  #pragma unroll 1
  for (int c2 = 0; c2 < mc; c2++) {
    int j = Jc[c2];
    int ridx = i - j + 256; ridx = ridx < 0 ? 0 : (ridx > 255 ? 255 : ridx);
    double t2 = qv * ((double)k32[((size_t)bh * Nn + j) * 64 + lane] +
                      (double)rel32[ridx * 64 + lane]);
    #pragma unroll
    for (int d = 1; d < 64; d <<= 1) t2 += __shfl_xor(t2, d);
    if (lane == 0) Sx[c2] = (float)t2;
  }
  asm volatile("" ::: "memory");

  // rank by exact score; numpy tie semantics (== vk kept)
  const int need = topk - base;
  float myx = (lane < mc) ? Sx[lane] : -3.0e38f;
  int rank = 0;
  #pragma unroll 1
  for (int c2 = 0; c2 < mc; c2++) {
    float o = Sx[c2];
    rank += (o > myx || (o == myx && c2 < lane)) ? 1 : 0;
  }
  unsigned long long bm = __ballot((lane < mc) && (rank == need - 1));
  float vk = bm ? __shfl(myx, (int)__ffsll(bm) - 1) : 3.0e38f;
  bool ck = (lane < mc) && ((rank < need) || (myx == vk));
  unsigned long long km2 = __ballot(ck);
  float pb = 0.f;
  if (ck) {
    int pos = base + __popcll(km2 & lmlt);
    Pk[pos] = (unsigned int)Jc[lane];
    pb = __expf(myx - mxv);
    P2[pos] = pb;                        // boundary p exact (from f64 score)
  }
  const int nk = base + __popcll(km2);
  // exp for sure-keeps (from quantized codes) + denom
  float ps = pb;
  #pragma unroll 1
  for (int t = lane; t < base; t += 64) {
    float val = unmapf(Pk[t] >> 16);
    float p = __expf(val - mxv);
    P2[t] = p; ps += p;
  }
  #pragma unroll
  for (int d = 1; d < 64; d <<= 1) ps += __shfl_xor(ps, d);
  const float coef = gating[(size_t)b * Nn + i] / ps;
  asm volatile("" ::: "memory");

  // PV gather (f16 v), 4-deep ILP; first 64 guaranteed (nk >= topk = 64)
  const _Float16* vbp = vh + (size_t)bh * Nn * 64 + lane;
  float a0 = 0.f, a1 = 0.f, a2 = 0.f, a3 = 0.f;
  #pragma unroll 1
  for (int t = 0; t < 64; t += 4) {
    int j0 = (int)(Pk[t] & 0xffffu), j1 = (int)(Pk[t + 1] & 0xffffu);
    int j2 = (int)(Pk[t + 2] & 0xffffu), j3 = (int)(Pk[t + 3] & 0xffffu);
    float p0 = P2[t], p1 = P2[t + 1], p2 = P2[t + 2], p3 = P2[t + 3];
    a0 += p0 * (float)vbp[(size_t)j0 * 64];
    a1 += p1 * (float)vbp[(size_t)j1 * 64];
    a2 += p2 * (float)vbp[(size_t)j2 * 64];
    a3 += p3 * (float)vbp[(size_t)j3 * 64];
  }
  #pragma unroll 1
  for (int t = 64; t < nk; t++)
    a0 += P2[t] * (float)vbp[(size_t)(Pk[t] & 0xffffu) * 64];
  inner[((size_t)b * Nn + i) * 1024 + h * 64 + lane] = (a0 + a1 + a2 + a3) * coef;
}

extern "C" void kernel_launch(void* const* d_in, const int* in_sizes, int n_in,
                              void* d_out, int out_size, void* d_ws, size_t ws_size,
                              hipStream_t stream) {
  const float* x      = (const float*)d_in[0];
  const float* gating = (const float*)d_in[1];
  const float* Wq     = (const float*)d_in[2];
  const float* bq     = (const float*)d_in[3];
  const float* Wkv    = (const float*)d_in[4];
  const float* bkv    = (const float*)d_in[5];
  const float* Wo     = (const float*)d_in[6];
  const float* bo     = (const float*)d_in[7];
  const float* rel    = (const float*)d_in[8];
  const int*   topk   = (const int*)d_in[10];
  float* out = (float*)d_out;

  char* ws = (char*)d_ws;
  size_t off = 0;
  auto alloc = [&](size_t bytes) -> void* {
    void* p = ws + off; off += (bytes + 255) & ~(size_t)255; return p;
  };
  unsigned short* Wqt0 = (unsigned short*)alloc(1024ull * 1024 * 2);
  unsigned short* Wqt1 = (unsigned short*)alloc(1024ull * 1024 * 2);
  unsigned short* Wqt2 = (unsigned short*)alloc(1024ull * 1024 * 2);
  unsigned short* Wkt0 = (unsigned short*)alloc(2048ull * 1024 * 2);
  unsigned short* Wkt1 = (unsigned short*)alloc(2048ull * 1024 * 2);
  unsigned short* Wkt2 = (unsigned short*)alloc(2048ull * 1024 * 2);
  unsigned short* Wot0 = (unsigned short*)alloc(1024ull * 1024 * 2);
  unsigned short* Wot1 = (unsigned short*)alloc(1024ull * 1024 * 2);
  unsigned short* relbf = (unsigned short*)alloc(256ull * 64 * 2);
  float* q32 = (float*)alloc((size_t)BHn * Nn * 64 * 4);
  float* k32 = (float*)alloc((size_t)BHn * Nn * 64 * 4);
  unsigned short* qhb = (unsigned short*)alloc((size_t)BHn * Nn * 64 * 2);
  unsigned short* qmb = (unsigned short*)alloc((size_t)BHn * Nn * 64 * 2);
  unsigned short* khb = (unsigned short*)alloc((size_t)BHn * Nn * 64 * 2);
  unsigned short* kmb = (unsigned short*)alloc((size_t)BHn * Nn * 64 * 2);
  _Float16* vhb = (_Float16*)alloc((size_t)BHn * Nn * 64 * 2);
  float* inner = (float*)alloc((size_t)Bn * Nn * 1024 * 4);
  if (off > ws_size) return;  // workspace too small -> loud validation fail

  size_t shmem = 65536 + 16384;  // 81920 B -> 2 WG/CU (160 KiB total)
  (void)hipFuncSetAttribute((const void*)attn_k,
                            hipFuncAttributeMaxDynamicSharedMemorySize, (int)shmem);

  transpose_split3<<<dim3(32, 32), 256, 0, stream>>>(Wq, Wqt0, Wqt1, Wqt2, 1024, 1024);
  transpose_split3<<<dim3(64, 32), 256, 0, stream>>>(Wkv, Wkt0, Wkt1, Wkt2, 1024, 2048);
  transpose_split2<<<dim3(32, 32), 256, 0, stream>>>(Wo, Wot0, Wot1, 1024, 1024);
  convert_bf16<<<dim3(64), 256, 0, stream>>>(rel, relbf, 256 * 64);

  // q = (x@Wq + bq) * 1/8  (scale folded; exact pow2)
  gemm_qkv<<<dim3(8, 64), 256, 0, stream>>>(x, Wqt0, Wqt1, Wqt2, bq,
      q32, qhb, qmb, vhb, 1024, 0.125f);
  // k | v = x@Wkv + bkv
  gemm_qkv<<<dim3(16, 64), 256, 0, stream>>>(x, Wkt0, Wkt1, Wkt2, bkv,
      k32, khb, kmb, vhb, 1024, 1.0f);

  attn_k<<<dim3(8192), 1024, shmem, stream>>>(qhb, qmb, khb, kmb, vhb,
      q32, k32, relbf, rel, gating, topk, inner);

  // out = inner@Wo + bo
  gemm_out<<<dim3(8, 64), 256, 0, stream>>>(inner, Wot0, Wot1, bo,
      out, 1024, 1024);
}